// Round 7
// baseline (798.549 us; speedup 1.0000x reference)
//
#include <hip/hip_runtime.h>

// Problem constants (fixed by the reference: N = 512*512, E = N*8, grid 512)
#define NN 262144
#define NE 2097152
constexpr int GS = 512;
constexpr int P  = GS * GS;   // == NN
constexpr int BSTRIDE = 12288; // per-bucket ssrc slot stride (4-aligned segs)

typedef __attribute__((ext_vector_type(16))) float f32x16;
typedef __attribute__((ext_vector_type(8)))  float f32x8;
typedef __attribute__((ext_vector_type(4)))  float f32x4;
typedef __attribute__((ext_vector_type(2)))  float f32x2;

// Explicit scalar (SMEM) loads for wave-uniform conv weight reads.
__device__ __forceinline__ f32x16 sload16(const float* p) {
  f32x16 v;
  asm("s_load_dwordx16 %0, %1, 0x0\n\ts_waitcnt lgkmcnt(0)" : "=s"(v) : "s"(p));
  return v;
}
__device__ __forceinline__ f32x8 sload8(const float* p) {
  f32x8 v;
  asm("s_load_dwordx8 %0, %1, 0x0\n\ts_waitcnt lgkmcnt(0)" : "=s"(v) : "s"(p));
  return v;
}
__device__ __forceinline__ f32x4 sload4(const float* p) {
  f32x4 v;
  asm("s_load_dwordx4 %0, %1, 0x0\n\ts_waitcnt lgkmcnt(0)" : "=s"(v) : "s"(p));
  return v;
}
__device__ __forceinline__ f32x2 sload2(const float* p) {
  f32x2 v;
  asm("s_load_dwordx2 %0, %1, 0x0\n\ts_waitcnt lgkmcnt(0)" : "=s"(v) : "s"(p));
  return v;
}

// ---------------------------------------------------------------------------
// CSR build, pass 1: 256-bucket histogram of dst>>10
// ---------------------------------------------------------------------------
__global__ __launch_bounds__(256) void k_bhist(const int4* __restrict__ dst,
                                               int* __restrict__ gb) {
  __shared__ int lc[256];
  int t = threadIdx.x;
  lc[t] = 0;
  __syncthreads();
  int base = blockIdx.x * 1024;            // int4 units; 4096 edges/block
#pragma unroll
  for (int q = 0; q < 4; ++q) {
    int4 d = dst[base + q * 256 + t];
    atomicAdd(&lc[d.x >> 10], 1); atomicAdd(&lc[d.y >> 10], 1);
    atomicAdd(&lc[d.z >> 10], 1); atomicAdd(&lc[d.w >> 10], 1);
  }
  __syncthreads();
  atomicAdd(&gb[t], lc[t]);
}

// exclusive scan of 256 bucket counts -> bbase[257]; copy to bcur
__global__ __launch_bounds__(256) void k_bscan(const int* __restrict__ gb,
                                               int* __restrict__ bbase,
                                               int* __restrict__ bcur) {
  __shared__ int sd[256];
  int t = threadIdx.x;
  sd[t] = gb[t];
  __syncthreads();
  for (int off = 1; off < 256; off <<= 1) {
    int v = (t >= off) ? sd[t - off] : 0;
    __syncthreads();
    sd[t] += v;
    __syncthreads();
  }
  int ex = (t == 0) ? 0 : sd[t - 1];
  bbase[t] = ex;
  bcur[t]  = ex;
  if (t == 255) bbase[256] = sd[255];
}

// pass 2: LDS-binned scatter of packed (dstLocal<<18 | src) into bucket runs.
__global__ __launch_bounds__(256) void k_bin(const int4* __restrict__ src4,
                                             const int4* __restrict__ dst4,
                                             int* __restrict__ bcur,
                                             unsigned* __restrict__ pairs) {
  __shared__ int lcnt[256], lofs[256], lcur[256];
  __shared__ unsigned lp[4096];
  int t = threadIdx.x;
  lcnt[t] = 0;
  __syncthreads();
  int base = blockIdx.x * 1024;
  int4 dreg[4], sreg[4];
#pragma unroll
  for (int q = 0; q < 4; ++q) {
    dreg[q] = dst4[base + q * 256 + t];
    sreg[q] = src4[base + q * 256 + t];
  }
#pragma unroll
  for (int q = 0; q < 4; ++q) {
    atomicAdd(&lcnt[dreg[q].x >> 10], 1); atomicAdd(&lcnt[dreg[q].y >> 10], 1);
    atomicAdd(&lcnt[dreg[q].z >> 10], 1); atomicAdd(&lcnt[dreg[q].w >> 10], 1);
  }
  __syncthreads();
  int c = lcnt[t];
  lofs[t] = c;
  __syncthreads();
  for (int off = 1; off < 256; off <<= 1) {
    int v = (t >= off) ? lofs[t - off] : 0;
    __syncthreads();
    lofs[t] += v;
    __syncthreads();
  }
  int myofs = lofs[t] - c;
  lcur[t] = myofs;
  int gb = atomicAdd(&bcur[t], c);
  __syncthreads();
#pragma unroll
  for (int q = 0; q < 4; ++q) {
    int d[4] = {dreg[q].x, dreg[q].y, dreg[q].z, dreg[q].w};
    int s[4] = {sreg[q].x, sreg[q].y, sreg[q].z, sreg[q].w};
#pragma unroll
    for (int j = 0; j < 4; ++j) {
      int pos = atomicAdd(&lcur[d[j] >> 10], 1);
      lp[pos] = ((unsigned)(d[j] & 1023) << 18) | (unsigned)s[j];
    }
  }
  __syncthreads();
  for (int k = 0; k < c; ++k) pairs[gb + k] = lp[myofs + k];
}

// pass 3: per-bucket counting sort. 4-ALIGNED per-node segments at fixed
// bucket stride; pads = NN (zero row). Direct global scatter (L2-local).
__global__ __launch_bounds__(256) void k_bsort(const unsigned* __restrict__ pairs,
                                               const int* __restrict__ bbase,
                                               int* __restrict__ ssrc,
                                               int* __restrict__ offs,
                                               int* __restrict__ dgr,
                                               float* __restrict__ dinv) {
  __shared__ int cnt[1024], ofs[1024], sblk[256];
  int b = blockIdx.x, t = threadIdx.x;
  int s0 = bbase[b], n = bbase[b + 1] - s0;
  int gbase = b * BSTRIDE;
  // init pad region (pads read as zero-row index)
  for (int i = t; i < BSTRIDE; i += 256) ssrc[gbase + i] = NN;
  for (int i = t; i < 1024; i += 256) cnt[i] = 0;
  __syncthreads();
  for (int i = t; i < n; i += 256) {
    unsigned p = pairs[s0 + i];
    atomicAdd(&cnt[p >> 18], 1);
  }
  __syncthreads();
  int l4 = t * 4;
  int c0 = cnt[l4], c1 = cnt[l4 + 1], c2 = cnt[l4 + 2], c3 = cnt[l4 + 3];
  int a0 = (c0 + 3) & ~3, a1 = (c1 + 3) & ~3, a2 = (c2 + 3) & ~3, a3 = (c3 + 3) & ~3;
  int sum = a0 + a1 + a2 + a3;
  sblk[t] = sum;
  __syncthreads();
  for (int off = 1; off < 256; off <<= 1) {
    int v = (t >= off) ? sblk[t - off] : 0;
    __syncthreads();
    sblk[t] += v;
    __syncthreads();
  }
  int ex = sblk[t] - sum;
  int o0 = gbase + ex, o1 = o0 + a0, o2 = o1 + a1, o3 = o2 + a2;
  ofs[l4] = o0; ofs[l4 + 1] = o1; ofs[l4 + 2] = o2; ofs[l4 + 3] = o3;
  int node = b * 1024 + l4;
  *(int4*)&offs[node] = make_int4(o0, o1, o2, o3);
  *(int4*)&dgr[node]  = make_int4(c0, c1, c2, c3);
  *(float4*)&dinv[node] = make_float4(rsqrtf((float)(c0 + 1)),
                                      rsqrtf((float)(c1 + 1)),
                                      rsqrtf((float)(c2 + 1)),
                                      rsqrtf((float)(c3 + 1)));
  __syncthreads();   // drains init stores before scatter overwrites
  for (int i = t; i < n; i += 256) {
    unsigned p = pairs[s0 + i];
    int pos = atomicAdd(&ofs[p >> 18], 1);
    ssrc[pos] = (int)(p & 0x3FFFFu);
  }
}

// ---------------------------------------------------------------------------
// GCN compute
// ---------------------------------------------------------------------------
// zero rows at index NN (gather target for masked slots)
__global__ void k_zrows(float* hA, float* hB, float* xs) {
  int t = threadIdx.x;
  if (t < 64) hA[(size_t)NN * 64 + t] = 0.f;
  else if (t < 128) hB[(size_t)NN * 64 + (t - 64)] = 0.f;
  else if (t < 132) xs[(size_t)NN * 4 + (t - 128)] = 0.f;
}

// xs = dinv * x  (pre-scaled features)
__global__ __launch_bounds__(256) void k_xscale(const float4* __restrict__ x,
                                                const float* __restrict__ dinv,
                                                float4* __restrict__ xs) {
  int i = blockIdx.x * 256 + threadIdx.x;
  float4 v = x[i];
  float d = dinv[i];
  xs[i] = make_float4(v.x * d, v.y * d, v.z * d, v.w * d);
}

// xagg_i = dinv_i * (sum_{s in N(i)} xs_s + xs_i)
__global__ __launch_bounds__(256) void k_agg4(const float4* __restrict__ xs,
                                              const float* __restrict__ dinv,
                                              const int* __restrict__ offs,
                                              const int* __restrict__ dgr,
                                              const int4* __restrict__ ssrc4,
                                              float4* __restrict__ out) {
  for (int i = blockIdx.x * 256 + threadIdx.x; i < NN; i += gridDim.x * 256) {
    float di = dinv[i];
    int k4 = offs[i] >> 2, deg = dgr[i];
    float4 acc = xs[i];
    int t4n = (deg + 3) >> 2;
    int4 s4 = ssrc4[k4];
    for (int t4 = 0; t4 < t4n; ++t4) {
      int4 nx = ssrc4[k4 + t4 + 1];
      int tb = t4 * 4;
#pragma unroll
      for (int j = 0; j < 4; ++j) {
        int s = (tb + j < deg) ? ((const int*)&s4)[j] : NN;
        float4 v = xs[s];
        acc.x += v.x; acc.y += v.y; acc.z += v.z; acc.w += v.w;
      }
      s4 = nx;
    }
    out[i] = make_float4(acc.x * di, acc.y * di, acc.z * di, acc.w * di);
  }
}

// h1' = relu(xagg @ W1 + b1) * dinv   (pre-scaled for layer-2 gather)
__global__ __launch_bounds__(256) void k_matmul4(const float* __restrict__ h,
                                                 const float* __restrict__ W,
                                                 const float* __restrict__ bias,
                                                 const float* __restrict__ dinv,
                                                 float* __restrict__ out) {
  int lane = threadIdx.x & 63;
  int wv   = threadIdx.x >> 6;
  float w0 = W[lane], w1 = W[64 + lane], w2 = W[128 + lane], w3 = W[192 + lane];
  float bl = bias[lane];
  for (int node = blockIdx.x * 4 + wv; node < NN; node += gridDim.x * 4) {
    float4 hv = *(const float4*)(h + (size_t)node * 4);
    float dn = dinv[node];
    float acc = fmaf(hv.x, w0, fmaf(hv.y, w1, fmaf(hv.z, w2, fmaf(hv.w, w3, bl))));
    out[(size_t)node * 64 + lane] = fmaxf(acc, 0.f) * dn;
  }
}

// Fused GCN layer on pre-scaled rows h' : out = relu( (di * sum h'_s) W + b )
// [* dinv if SCALE_OUT]. 4 nodes/wave; int4 edge indices w/ prefetch; masked
// slots -> zero row NN. Matvec: rotation reads of duplicated 512B LDS row
// against diagonal-rotated W per-lane in VGPRs.
template <bool SCALE_OUT>
__global__ __launch_bounds__(256) void k_aggW(const float* __restrict__ h,
                                              const float* __restrict__ dinv,
                                              const int* __restrict__ offs,
                                              const int* __restrict__ dgr,
                                              const int4* __restrict__ ssrc4,
                                              const float* __restrict__ W,
                                              const float* __restrict__ bias,
                                              float* __restrict__ out) {
  __shared__ float g[16][128];               // duplicated rows: [d] and [d+64]
  const float4* h4 = (const float4*)h;
  int lane = threadIdx.x & 63;
  int wv   = threadIdx.x >> 6;
  int sub  = lane >> 4;        // node slot (0..3)
  int fl   = lane & 15;        // float4 index within row
  int rot  = lane & 15;        // rotation base for matvec
  // diagonal-rotated weights: wrot[q*4+j] = W[4*((rot+q)&15)+j][lane]
  float wrot[64];
#pragma unroll
  for (int q = 0; q < 16; ++q) {
    int kb = 4 * ((rot + q) & 15);
#pragma unroll
    for (int j = 0; j < 4; ++j) wrot[q * 4 + j] = W[(size_t)(kb + j) * 64 + lane];
  }
  float bl = bias[lane];

  for (int i0 = (blockIdx.x * 4 + wv) * 4; i0 < NN; i0 += gridDim.x * 16) {
    int i = i0 + sub;
    float di = dinv[i];
    int k4 = offs[i] >> 2;
    int deg = dgr[i];
    int m = deg;
    m = max(m, __shfl_xor(m, 16));
    m = max(m, __shfl_xor(m, 32));

    float4 acc = h4[(size_t)i * 16 + fl];    // self term (h' already scaled)
    int t4n = (m + 3) >> 2;
    int4 s4 = ssrc4[k4];
#pragma unroll 2
    for (int t4 = 0; t4 < t4n; ++t4) {
      int4 nx = ssrc4[k4 + t4 + 1];
      int tb = t4 * 4;
#pragma unroll
      for (int j = 0; j < 4; ++j) {
        int s = (tb + j < deg) ? ((const int*)&s4)[j] : NN;
        float4 v = h4[(size_t)s * 16 + fl];
        acc.x += v.x; acc.y += v.y; acc.z += v.z; acc.w += v.w;
      }
      s4 = nx;
    }

    // park di*acc twice (no-wrap rotation window)
    float4 sacc = make_float4(acc.x * di, acc.y * di, acc.z * di, acc.w * di);
    int row = wv * 4 + sub;
    *(float4*)&g[row][fl * 4]      = sacc;
    *(float4*)&g[row][fl * 4 + 64] = sacc;
    asm volatile("s_waitcnt lgkmcnt(0)" ::: "memory");

#pragma unroll
    for (int n = 0; n < 4; ++n) {
      const float4* gp = (const float4*)&g[wv * 4 + n][rot * 4];
      float o = bl;
#pragma unroll
      for (int q = 0; q < 16; ++q) {
        float4 gv = gp[q];
        o = fmaf(gv.x, wrot[q * 4 + 0], o);
        o = fmaf(gv.y, wrot[q * 4 + 1], o);
        o = fmaf(gv.z, wrot[q * 4 + 2], o);
        o = fmaf(gv.w, wrot[q * 4 + 3], o);
      }
      float val = fmaxf(o, 0.f);
      if (SCALE_OUT) val *= dinv[i0 + n];
      out[(size_t)(i0 + n) * 64 + lane] = val;
    }
  }
}

// channels-last [P][64] -> planar [64][P]
__global__ __launch_bounds__(256) void k_transpose(const float* __restrict__ in,
                                                   float* __restrict__ out) {
  __shared__ float t[64][65];
  int tx = threadIdx.x & 63;
  int ty = threadIdx.x >> 6;
  int base = blockIdx.x * 64;
#pragma unroll
  for (int i = 0; i < 16; ++i) {
    int p = ty + i * 4;
    t[p][tx] = in[(size_t)(base + p) * 64 + tx];
  }
  __syncthreads();
#pragma unroll
  for (int i = 0; i < 16; ++i) {
    int c = ty + i * 4;
    out[(size_t)c * P + base + tx] = t[tx][c];
  }
}

// Repack conv weights OIHW -> [c][tap][o]
template <int CIN, int COUT>
__global__ __launch_bounds__(256) void k_wrep(const float* __restrict__ w,
                                              float* __restrict__ wr) {
  int i = blockIdx.x * 256 + threadIdx.x;
  if (i >= CIN * 9 * COUT) return;
  int o = i % COUT;
  int t = (i / COUT) % 9;
  int c = i / (COUT * 9);
  wr[i] = w[(o * CIN + c) * 9 + t];
}

// ---------------------------------------------------------------------------
// Planar 3x3 SAME conv, 4 px/thread (float4 interior), COUTB outs per block.
// Weights via s_load->SGPR; next-channel inputs prefetched (2x manual unroll,
// static register buffers only).
// ---------------------------------------------------------------------------
template <int CIN, int COUT, int COUTB, bool RELU>
struct ConvOps {
  __device__ static __forceinline__ void load(const float* __restrict__ in,
                                              int c, const int* yoff,
                                              const int* rok, bool xlo, bool xhi,
                                              int x0, float (&iv)[3][6]) {
#pragma unroll
    for (int r = 0; r < 3; ++r) {
      const float* ip = in + (size_t)c * P + yoff[r] + x0;
      if (rok[r]) {
        float4 m = *(const float4*)ip;
        iv[r][1] = m.x; iv[r][2] = m.y; iv[r][3] = m.z; iv[r][4] = m.w;
        iv[r][0] = xlo ? ip[-1] : 0.f;
        iv[r][5] = xhi ? ip[4]  : 0.f;
      } else {
        iv[r][0] = iv[r][1] = iv[r][2] = iv[r][3] = iv[r][4] = iv[r][5] = 0.f;
      }
    }
  }
  __device__ static __forceinline__ void taps(const float* __restrict__ wc,
                                              const float (&iv)[3][6],
                                              float (&acc)[4][COUTB]) {
#pragma unroll
    for (int t9 = 0; t9 < 9; ++t9) {
      const int ky = t9 / 3, kx = t9 % 3;
      const float* wp = wc + t9 * COUT;
      if constexpr (COUTB == 16) {
        f32x16 wv = sload16(wp);
#pragma unroll
        for (int o = 0; o < 16; ++o)
#pragma unroll
          for (int p = 0; p < 4; ++p)
            acc[p][o] = fmaf(iv[ky][kx + p], wv[o], acc[p][o]);
      } else if constexpr (COUTB == 8) {
        f32x8 wv = sload8(wp);
#pragma unroll
        for (int o = 0; o < 8; ++o)
#pragma unroll
          for (int p = 0; p < 4; ++p)
            acc[p][o] = fmaf(iv[ky][kx + p], wv[o], acc[p][o]);
      } else if constexpr (COUTB == 6) {
        f32x4 wv = sload4(wp);
        f32x2 wu = sload2(wp + 4);
#pragma unroll
        for (int o = 0; o < 4; ++o)
#pragma unroll
          for (int p = 0; p < 4; ++p)
            acc[p][o] = fmaf(iv[ky][kx + p], wv[o], acc[p][o]);
#pragma unroll
        for (int o = 0; o < 2; ++o)
#pragma unroll
          for (int p = 0; p < 4; ++p)
            acc[p][4 + o] = fmaf(iv[ky][kx + p], wu[o], acc[p][4 + o]);
      }
    }
  }
};

template <int CIN, int COUT, int COUTB, bool RELU>
__global__ __launch_bounds__(256) void k_conv(const float* __restrict__ in,
                                              const float* __restrict__ wrep,
                                              const float* __restrict__ cb,
                                              float* __restrict__ out) {
  using Ops = ConvOps<CIN, COUT, COUTB, RELU>;
  int tx = threadIdx.x;          // 0..63
  int ty = threadIdx.y;          // 0..3
  int g  = blockIdx.z;
  int x0 = (blockIdx.x * 64 + tx) * 4;
  int y  = blockIdx.y * 4 + ty;

  float acc[4][COUTB];
#pragma unroll
  for (int p = 0; p < 4; ++p)
#pragma unroll
    for (int o = 0; o < COUTB; ++o) acc[p][o] = 0.f;

  bool xlo = x0 > 0;
  bool xhi = x0 < GS - 4;
  int rok[3], yoff[3];
#pragma unroll
  for (int r = 0; r < 3; ++r) {
    int yy = y + r - 1;
    rok[r] = (yy >= 0) && (yy < GS);
    int yc = yy < 0 ? 0 : (yy > GS - 1 ? GS - 1 : yy);
    yoff[r] = yc * GS;
  }
  const float* wg = wrep + g * COUTB;

  float iva[3][6], ivb[3][6];
  Ops::load(in, 0, yoff, rok, xlo, xhi, x0, iva);
#pragma unroll 1
  for (int c = 0; c < CIN; c += 2) {
    Ops::load(in, c + 1, yoff, rok, xlo, xhi, x0, ivb);   // prefetch c+1
    Ops::taps(wg + (size_t)c * 9 * COUT, iva, acc);
    if (c + 2 < CIN)
      Ops::load(in, c + 2, yoff, rok, xlo, xhi, x0, iva); // prefetch c+2
    Ops::taps(wg + (size_t)(c + 1) * 9 * COUT, ivb, acc);
  }

  size_t obase = (size_t)(g * COUTB) * P + (size_t)y * GS + x0;
#pragma unroll
  for (int o = 0; o < COUTB; ++o) {
    float bv = cb[g * COUTB + o];
    float4 v;
    v.x = acc[0][o] + bv; v.y = acc[1][o] + bv;
    v.z = acc[2][o] + bv; v.w = acc[3][o] + bv;
    if (RELU) {
      v.x = fmaxf(v.x, 0.f); v.y = fmaxf(v.y, 0.f);
      v.z = fmaxf(v.z, 0.f); v.w = fmaxf(v.w, 0.f);
    }
    *(float4*)&out[obase + (size_t)o * P] = v;
  }
}

// ---------------------------------------------------------------------------
extern "C" void kernel_launch(void* const* d_in, const int* in_sizes, int n_in,
                              void* d_out, int out_size, void* d_ws, size_t ws_size,
                              hipStream_t stream) {
  const float* x   = (const float*)d_in[0];
  const int*   esr = (const int*)d_in[1];
  const int*   eds = (const int*)d_in[2];
  const float* W1  = (const float*)d_in[4];
  const float* b1  = (const float*)d_in[5];
  const float* W2  = (const float*)d_in[6];
  const float* b2  = (const float*)d_in[7];
  const float* W3  = (const float*)d_in[8];
  const float* b3  = (const float*)d_in[9];
  const float* cw1 = (const float*)d_in[10];
  const float* cb1 = (const float*)d_in[11];
  const float* cw2 = (const float*)d_in[12];
  const float* cb2 = (const float*)d_in[13];
  const float* cw3 = (const float*)d_in[14];
  const float* cb3 = (const float*)d_in[15];
  const float* cw4 = (const float*)d_in[16];
  const float* cb4 = (const float*)d_in[17];
  float* out = (float*)d_out;

  char* ws = (char*)d_ws;
  const size_t MB = 1 << 20;
  const size_t KB = 1 << 10;
  // Region A [0,65MB): pairs -> xs -> hA (temporally disjoint, stream order)
  unsigned* pairs = (unsigned*)(ws);                 // 8 MB (dead after bsort)
  float*    xs    = (float*)(ws);                    // 4 MB+16B (dead after agg4)
  float*    hA    = (float*)(ws);                    // 64 MB+256B
  // Region B [65MB,130MB): xagg -> hB
  float*    xagg  = (float*)(ws + 65 * MB);          // 4 MB (dead after matmul4)
  float*    hB    = (float*)(ws + 65 * MB);          // 64 MB+256B
  int*      ssrc  = (int*)(ws + 130 * MB);           // 12 MB + margin
  float*    dinv  = (float*)(ws + 142 * MB + 8 * KB);   // 1 MB
  int*      dgr   = (int*)(ws + 143 * MB + 16 * KB);    // 1 MB
  int*      offs  = (int*)(ws + 144 * MB + 24 * KB);    // 1 MB
  int*      gb    = (int*)(ws + 145 * MB + 32 * KB);    // 1 KB
  int*      bbase = (int*)(ws + 145 * MB + 36 * KB);    // 1 KB + 4
  int*      bcur  = (int*)(ws + 145 * MB + 40 * KB);    // 1 KB
  float*    wr1   = (float*)(ws + 145 * MB + 48 * KB);  // 72 KB
  float*    wr2   = wr1 + 64 * 9 * 32;
  float*    wr3   = wr2 + 32 * 9 * 16;
  float*    wr4   = wr3 + 16 * 9 * 8;

  // ---- conv weight repacks ----
  k_wrep<64, 32><<<(64 * 9 * 32 + 255) / 256, 256, 0, stream>>>(cw1, wr1);
  k_wrep<32, 16><<<(32 * 9 * 16 + 255) / 256, 256, 0, stream>>>(cw2, wr2);
  k_wrep<16,  8><<<(16 * 9 *  8 + 255) / 256, 256, 0, stream>>>(cw3, wr3);
  k_wrep< 8,  6><<<( 8 * 9 *  6 + 255) / 256, 256, 0, stream>>>(cw4, wr4);

  // ---- CSR build ----
  hipMemsetAsync(gb, 0, 256 * sizeof(int), stream);
  k_bhist<<<512, 256, 0, stream>>>((const int4*)eds, gb);
  k_bscan<<<1, 256, 0, stream>>>(gb, bbase, bcur);
  k_bin<<<512, 256, 0, stream>>>((const int4*)esr, (const int4*)eds, bcur, pairs);
  k_bsort<<<256, 256, 0, stream>>>(pairs, bbase, ssrc, offs, dgr, dinv);

  // ---- GCN ----
  k_zrows<<<1, 256, 0, stream>>>(hA, hB, xs);
  k_xscale<<<NN / 256, 256, 0, stream>>>((const float4*)x, dinv, (float4*)xs);
  k_agg4<<<1024, 256, 0, stream>>>((const float4*)xs, dinv, offs, dgr,
                                   (const int4*)ssrc, (float4*)xagg);
  k_matmul4<<<2048, 256, 0, stream>>>(xagg, W1, b1, dinv, hA);
  k_aggW<true ><<<2048, 256, 0, stream>>>(hA, dinv, offs, dgr,
                                          (const int4*)ssrc, W2, b2, hB);
  k_aggW<false><<<2048, 256, 0, stream>>>(hB, dinv, offs, dgr,
                                          (const int4*)ssrc, W3, b3, hA);

  // ---- CNN ----
  k_transpose<<<NN / 64, 256, 0, stream>>>(hA, hB);   // [P][64] -> [64][P]
  dim3 cblk(64, 4);
  k_conv<64, 32, 16, true ><<<dim3(2, 128, 2), cblk, 0, stream>>>(hB, wr1, cb1, hA);
  k_conv<32, 16, 16, true ><<<dim3(2, 128, 1), cblk, 0, stream>>>(hA, wr2, cb2, hB);
  k_conv<16,  8,  8, true ><<<dim3(2, 128, 1), cblk, 0, stream>>>(hB, wr3, cb3, hA);
  k_conv< 8,  6,  6, false><<<dim3(2, 128, 1), cblk, 0, stream>>>(hA, wr4, cb4, out);
}

// Round 8
// 785.918 us; speedup vs baseline: 1.0161x; 1.0161x over previous
//
#include <hip/hip_runtime.h>

// Problem constants (fixed by the reference: N = 512*512, E = N*8, grid 512)
#define NN 262144
#define NE 2097152
constexpr int GS = 512;
constexpr int P  = GS * GS;   // == NN
constexpr int BSTRIDE = 12288; // per-bucket ssrc slot stride (4-aligned segs)

typedef __attribute__((ext_vector_type(16))) float f32x16;
typedef __attribute__((ext_vector_type(8)))  float f32x8;
typedef __attribute__((ext_vector_type(4)))  float f32x4;
typedef __attribute__((ext_vector_type(2)))  float f32x2;

// Explicit scalar (SMEM) loads for wave-uniform conv weight reads.
__device__ __forceinline__ f32x16 sload16(const float* p) {
  f32x16 v;
  asm("s_load_dwordx16 %0, %1, 0x0\n\ts_waitcnt lgkmcnt(0)" : "=s"(v) : "s"(p));
  return v;
}
__device__ __forceinline__ f32x8 sload8(const float* p) {
  f32x8 v;
  asm("s_load_dwordx8 %0, %1, 0x0\n\ts_waitcnt lgkmcnt(0)" : "=s"(v) : "s"(p));
  return v;
}
__device__ __forceinline__ f32x4 sload4(const float* p) {
  f32x4 v;
  asm("s_load_dwordx4 %0, %1, 0x0\n\ts_waitcnt lgkmcnt(0)" : "=s"(v) : "s"(p));
  return v;
}
__device__ __forceinline__ f32x2 sload2(const float* p) {
  f32x2 v;
  asm("s_load_dwordx2 %0, %1, 0x0\n\ts_waitcnt lgkmcnt(0)" : "=s"(v) : "s"(p));
  return v;
}

// ---------------------------------------------------------------------------
// CSR build, pass 1: 256-bucket histogram of dst>>10
// ---------------------------------------------------------------------------
__global__ __launch_bounds__(256) void k_bhist(const int4* __restrict__ dst,
                                               int* __restrict__ gb) {
  __shared__ int lc[256];
  int t = threadIdx.x;
  lc[t] = 0;
  __syncthreads();
  int base = blockIdx.x * 1024;            // int4 units; 4096 edges/block
#pragma unroll
  for (int q = 0; q < 4; ++q) {
    int4 d = dst[base + q * 256 + t];
    atomicAdd(&lc[d.x >> 10], 1); atomicAdd(&lc[d.y >> 10], 1);
    atomicAdd(&lc[d.z >> 10], 1); atomicAdd(&lc[d.w >> 10], 1);
  }
  __syncthreads();
  atomicAdd(&gb[t], lc[t]);
}

// exclusive scan of 256 bucket counts -> bbase[257]; copy to bcur
__global__ __launch_bounds__(256) void k_bscan(const int* __restrict__ gb,
                                               int* __restrict__ bbase,
                                               int* __restrict__ bcur) {
  __shared__ int sd[256];
  int t = threadIdx.x;
  sd[t] = gb[t];
  __syncthreads();
  for (int off = 1; off < 256; off <<= 1) {
    int v = (t >= off) ? sd[t - off] : 0;
    __syncthreads();
    sd[t] += v;
    __syncthreads();
  }
  int ex = (t == 0) ? 0 : sd[t - 1];
  bbase[t] = ex;
  bcur[t]  = ex;
  if (t == 255) bbase[256] = sd[255];
}

// pass 2: LDS-binned scatter of packed (dstLocal<<18 | src) into bucket runs.
__global__ __launch_bounds__(256) void k_bin(const int4* __restrict__ src4,
                                             const int4* __restrict__ dst4,
                                             int* __restrict__ bcur,
                                             unsigned* __restrict__ pairs) {
  __shared__ int lcnt[256], lofs[256], lcur[256];
  __shared__ unsigned lp[4096];
  int t = threadIdx.x;
  lcnt[t] = 0;
  __syncthreads();
  int base = blockIdx.x * 1024;
  int4 dreg[4], sreg[4];
#pragma unroll
  for (int q = 0; q < 4; ++q) {
    dreg[q] = dst4[base + q * 256 + t];
    sreg[q] = src4[base + q * 256 + t];
  }
#pragma unroll
  for (int q = 0; q < 4; ++q) {
    atomicAdd(&lcnt[dreg[q].x >> 10], 1); atomicAdd(&lcnt[dreg[q].y >> 10], 1);
    atomicAdd(&lcnt[dreg[q].z >> 10], 1); atomicAdd(&lcnt[dreg[q].w >> 10], 1);
  }
  __syncthreads();
  int c = lcnt[t];
  lofs[t] = c;
  __syncthreads();
  for (int off = 1; off < 256; off <<= 1) {
    int v = (t >= off) ? lofs[t - off] : 0;
    __syncthreads();
    lofs[t] += v;
    __syncthreads();
  }
  int myofs = lofs[t] - c;
  lcur[t] = myofs;
  int gb = atomicAdd(&bcur[t], c);
  __syncthreads();
#pragma unroll
  for (int q = 0; q < 4; ++q) {
    int d[4] = {dreg[q].x, dreg[q].y, dreg[q].z, dreg[q].w};
    int s[4] = {sreg[q].x, sreg[q].y, sreg[q].z, sreg[q].w};
#pragma unroll
    for (int j = 0; j < 4; ++j) {
      int pos = atomicAdd(&lcur[d[j] >> 10], 1);
      lp[pos] = ((unsigned)(d[j] & 1023) << 18) | (unsigned)s[j];
    }
  }
  __syncthreads();
  for (int k = 0; k < c; ++k) pairs[gb + k] = lp[myofs + k];
}

// pass 3: per-bucket counting sort. 4-ALIGNED per-node segments at fixed
// bucket stride; pads = NN (zero row). Direct global scatter (L2-local).
__global__ __launch_bounds__(256) void k_bsort(const unsigned* __restrict__ pairs,
                                               const int* __restrict__ bbase,
                                               int* __restrict__ ssrc,
                                               int* __restrict__ offs,
                                               int* __restrict__ dgr,
                                               float* __restrict__ dinv) {
  __shared__ int cnt[1024], ofs[1024], sblk[256];
  int b = blockIdx.x, t = threadIdx.x;
  int s0 = bbase[b], n = bbase[b + 1] - s0;
  int gbase = b * BSTRIDE;
  // init pad region (pads read as zero-row index)
  for (int i = t; i < BSTRIDE; i += 256) ssrc[gbase + i] = NN;
  for (int i = t; i < 1024; i += 256) cnt[i] = 0;
  __syncthreads();
  for (int i = t; i < n; i += 256) {
    unsigned p = pairs[s0 + i];
    atomicAdd(&cnt[p >> 18], 1);
  }
  __syncthreads();
  int l4 = t * 4;
  int c0 = cnt[l4], c1 = cnt[l4 + 1], c2 = cnt[l4 + 2], c3 = cnt[l4 + 3];
  int a0 = (c0 + 3) & ~3, a1 = (c1 + 3) & ~3, a2 = (c2 + 3) & ~3, a3 = (c3 + 3) & ~3;
  int sum = a0 + a1 + a2 + a3;
  sblk[t] = sum;
  __syncthreads();
  for (int off = 1; off < 256; off <<= 1) {
    int v = (t >= off) ? sblk[t - off] : 0;
    __syncthreads();
    sblk[t] += v;
    __syncthreads();
  }
  int ex = sblk[t] - sum;
  int o0 = gbase + ex, o1 = o0 + a0, o2 = o1 + a1, o3 = o2 + a2;
  ofs[l4] = o0; ofs[l4 + 1] = o1; ofs[l4 + 2] = o2; ofs[l4 + 3] = o3;
  int node = b * 1024 + l4;
  *(int4*)&offs[node] = make_int4(o0, o1, o2, o3);
  *(int4*)&dgr[node]  = make_int4(c0, c1, c2, c3);
  *(float4*)&dinv[node] = make_float4(rsqrtf((float)(c0 + 1)),
                                      rsqrtf((float)(c1 + 1)),
                                      rsqrtf((float)(c2 + 1)),
                                      rsqrtf((float)(c3 + 1)));
  __syncthreads();   // drains init stores before scatter overwrites
  for (int i = t; i < n; i += 256) {
    unsigned p = pairs[s0 + i];
    int pos = atomicAdd(&ofs[p >> 18], 1);
    ssrc[pos] = (int)(p & 0x3FFFFu);
  }
}

// ---------------------------------------------------------------------------
// GCN compute
// ---------------------------------------------------------------------------
// zero rows at index NN (gather target for masked slots)
__global__ void k_zrows(float* hA, float* hB, float* xs) {
  int t = threadIdx.x;
  if (t < 64) hA[(size_t)NN * 64 + t] = 0.f;
  else if (t < 128) hB[(size_t)NN * 64 + (t - 64)] = 0.f;
  else if (t < 132) xs[(size_t)NN * 4 + (t - 128)] = 0.f;
}

// xs = dinv * x  (pre-scaled features)
__global__ __launch_bounds__(256) void k_xscale(const float4* __restrict__ x,
                                                const float* __restrict__ dinv,
                                                float4* __restrict__ xs) {
  int i = blockIdx.x * 256 + threadIdx.x;
  float4 v = x[i];
  float d = dinv[i];
  xs[i] = make_float4(v.x * d, v.y * d, v.z * d, v.w * d);
}

// xagg_i = dinv_i * (sum_{s in N(i)} xs_s + xs_i)
__global__ __launch_bounds__(256) void k_agg4(const float4* __restrict__ xs,
                                              const float* __restrict__ dinv,
                                              const int* __restrict__ offs,
                                              const int* __restrict__ dgr,
                                              const int4* __restrict__ ssrc4,
                                              float4* __restrict__ out) {
  for (int i = blockIdx.x * 256 + threadIdx.x; i < NN; i += gridDim.x * 256) {
    float di = dinv[i];
    int k4 = offs[i] >> 2, deg = dgr[i];
    float4 acc = xs[i];
    int t4n = (deg + 3) >> 2;
    int4 s4 = ssrc4[k4];
    for (int t4 = 0; t4 < t4n; ++t4) {
      int4 nx = ssrc4[k4 + t4 + 1];
      int tb = t4 * 4;
#pragma unroll
      for (int j = 0; j < 4; ++j) {
        int s = (tb + j < deg) ? ((const int*)&s4)[j] : NN;
        float4 v = xs[s];
        acc.x += v.x; acc.y += v.y; acc.z += v.z; acc.w += v.w;
      }
      s4 = nx;
    }
    out[i] = make_float4(acc.x * di, acc.y * di, acc.z * di, acc.w * di);
  }
}

// h1' = relu(xagg @ W1 + b1) * dinv   (pre-scaled for layer-2 gather)
__global__ __launch_bounds__(256) void k_matmul4(const float* __restrict__ h,
                                                 const float* __restrict__ W,
                                                 const float* __restrict__ bias,
                                                 const float* __restrict__ dinv,
                                                 float* __restrict__ out) {
  int lane = threadIdx.x & 63;
  int wv   = threadIdx.x >> 6;
  float w0 = W[lane], w1 = W[64 + lane], w2 = W[128 + lane], w3 = W[192 + lane];
  float bl = bias[lane];
  for (int node = blockIdx.x * 4 + wv; node < NN; node += gridDim.x * 4) {
    float4 hv = *(const float4*)(h + (size_t)node * 4);
    float dn = dinv[node];
    float acc = fmaf(hv.x, w0, fmaf(hv.y, w1, fmaf(hv.z, w2, fmaf(hv.w, w3, bl))));
    out[(size_t)node * 64 + lane] = fmaxf(acc, 0.f) * dn;
  }
}

// Fused GCN layer on pre-scaled rows h' : out = relu( (di * sum h'_s) W + b )
// [* dinv if SCALE_OUT]. 4 nodes/wave; each 16-lane group iterates only its
// OWN ceil(deg/4) int4 slots (divergence exec-masked; ~20% fewer gathers than
// wave-max bound). Masked tail slots -> zero row NN. Matvec: rotation reads
// of duplicated 512B LDS row vs diagonal-rotated W per-lane in VGPRs.
template <bool SCALE_OUT>
__global__ __launch_bounds__(256) void k_aggW(const float* __restrict__ h,
                                              const float* __restrict__ dinv,
                                              const int* __restrict__ offs,
                                              const int* __restrict__ dgr,
                                              const int4* __restrict__ ssrc4,
                                              const float* __restrict__ W,
                                              const float* __restrict__ bias,
                                              float* __restrict__ out) {
  __shared__ float g[16][128];               // duplicated rows: [d] and [d+64]
  const float4* h4 = (const float4*)h;
  int lane = threadIdx.x & 63;
  int wv   = threadIdx.x >> 6;
  int sub  = lane >> 4;        // node slot (0..3)
  int fl   = lane & 15;        // float4 index within row
  int rot  = lane & 15;        // rotation base for matvec
  // diagonal-rotated weights: wrot[q*4+j] = W[4*((rot+q)&15)+j][lane]
  float wrot[64];
#pragma unroll
  for (int q = 0; q < 16; ++q) {
    int kb = 4 * ((rot + q) & 15);
#pragma unroll
    for (int j = 0; j < 4; ++j) wrot[q * 4 + j] = W[(size_t)(kb + j) * 64 + lane];
  }
  float bl = bias[lane];

  for (int i0 = (blockIdx.x * 4 + wv) * 4; i0 < NN; i0 += gridDim.x * 16) {
    int i = i0 + sub;
    float di = dinv[i];
    int k4 = offs[i] >> 2;
    int deg = dgr[i];
    int t4n = (deg + 3) >> 2;

    float4 acc = h4[(size_t)i * 16 + fl];    // self term (h' already scaled)
    int4 s4 = ssrc4[k4];
#pragma unroll 2
    for (int t4 = 0; t4 < t4n; ++t4) {
      int4 nx = ssrc4[k4 + t4 + 1];
      int tb = t4 * 4;
#pragma unroll
      for (int j = 0; j < 4; ++j) {
        int s = (tb + j < deg) ? ((const int*)&s4)[j] : NN;
        float4 v = h4[(size_t)s * 16 + fl];
        acc.x += v.x; acc.y += v.y; acc.z += v.z; acc.w += v.w;
      }
      s4 = nx;
    }

    // park di*acc twice (no-wrap rotation window)
    float4 sacc = make_float4(acc.x * di, acc.y * di, acc.z * di, acc.w * di);
    int row = wv * 4 + sub;
    *(float4*)&g[row][fl * 4]      = sacc;
    *(float4*)&g[row][fl * 4 + 64] = sacc;
    asm volatile("s_waitcnt lgkmcnt(0)" ::: "memory");

#pragma unroll
    for (int n = 0; n < 4; ++n) {
      const float4* gp = (const float4*)&g[wv * 4 + n][rot * 4];
      float o = bl;
#pragma unroll
      for (int q = 0; q < 16; ++q) {
        float4 gv = gp[q];
        o = fmaf(gv.x, wrot[q * 4 + 0], o);
        o = fmaf(gv.y, wrot[q * 4 + 1], o);
        o = fmaf(gv.z, wrot[q * 4 + 2], o);
        o = fmaf(gv.w, wrot[q * 4 + 3], o);
      }
      float val = fmaxf(o, 0.f);
      if (SCALE_OUT) val *= dinv[i0 + n];
      out[(size_t)(i0 + n) * 64 + lane] = val;
    }
  }
}

// channels-last [P][64] -> planar [64][P]
__global__ __launch_bounds__(256) void k_transpose(const float* __restrict__ in,
                                                   float* __restrict__ out) {
  __shared__ float t[64][65];
  int tx = threadIdx.x & 63;
  int ty = threadIdx.x >> 6;
  int base = blockIdx.x * 64;
#pragma unroll
  for (int i = 0; i < 16; ++i) {
    int p = ty + i * 4;
    t[p][tx] = in[(size_t)(base + p) * 64 + tx];
  }
  __syncthreads();
#pragma unroll
  for (int i = 0; i < 16; ++i) {
    int c = ty + i * 4;
    out[(size_t)c * P + base + tx] = t[tx][c];
  }
}

// Repack conv weights OIHW -> [c][tap][o]
template <int CIN, int COUT>
__global__ __launch_bounds__(256) void k_wrep(const float* __restrict__ w,
                                              float* __restrict__ wr) {
  int i = blockIdx.x * 256 + threadIdx.x;
  if (i >= CIN * 9 * COUT) return;
  int o = i % COUT;
  int t = (i / COUT) % 9;
  int c = i / (COUT * 9);
  wr[i] = w[(o * CIN + c) * 9 + t];
}

// ---------------------------------------------------------------------------
// Planar 3x3 SAME conv, 2 px/thread, COUTB output channels per block
// (blockIdx.z = output-channel group). Weights via s_load -> SGPR.
// Small COUTB + high z-split => many blocks => occupancy hides sload waits.
// ---------------------------------------------------------------------------
template <int CIN, int COUT, int COUTB, bool RELU>
__global__ __launch_bounds__(256) void k_conv(const float* __restrict__ in,
                                              const float* __restrict__ wrep,
                                              const float* __restrict__ cb,
                                              float* __restrict__ out) {
  int tx = threadIdx.x;          // 0..63
  int ty = threadIdx.y;          // 0..3
  int g  = blockIdx.z;
  int x0 = (blockIdx.x * 64 + tx) * 2;
  int y  = blockIdx.y * 4 + ty;

  float acc0[COUTB], acc1[COUTB];
#pragma unroll
  for (int o = 0; o < COUTB; ++o) { acc0[o] = 0.f; acc1[o] = 0.f; }

  bool xlo = x0 > 0;
  bool xhi = x0 < GS - 2;
  int rok[3], yoff[3];
#pragma unroll
  for (int r = 0; r < 3; ++r) {
    int yy = y + r - 1;
    rok[r] = (yy >= 0) && (yy < GS);
    int yc = yy < 0 ? 0 : (yy > GS - 1 ? GS - 1 : yy);
    yoff[r] = yc * GS;
  }
  const float* wg = wrep + g * COUTB;

#pragma unroll 1
  for (int c = 0; c < CIN; ++c) {
    float iv[3][4];
#pragma unroll
    for (int r = 0; r < 3; ++r) {
      const float* ip = in + (size_t)c * P + yoff[r] + x0;
      if (rok[r]) {
        float2 m = *(const float2*)ip;
        iv[r][1] = m.x; iv[r][2] = m.y;
        iv[r][0] = xlo ? ip[-1] : 0.f;
        iv[r][3] = xhi ? ip[2]  : 0.f;
      } else {
        iv[r][0] = iv[r][1] = iv[r][2] = iv[r][3] = 0.f;
      }
    }
    const float* wc = wg + (size_t)c * 9 * COUT;
#pragma unroll
    for (int t9 = 0; t9 < 9; ++t9) {
      int ky = t9 / 3, kx = t9 % 3;
      float a = iv[ky][kx], b2 = iv[ky][kx + 1];
      const float* wp = wc + t9 * COUT;
      if constexpr (COUTB == 16) {
        f32x16 wv = sload16(wp);
#pragma unroll
        for (int o = 0; o < 16; ++o) {
          acc0[o] = fmaf(a, wv[o], acc0[o]);
          acc1[o] = fmaf(b2, wv[o], acc1[o]);
        }
      } else if constexpr (COUTB == 8) {
        f32x8 wv = sload8(wp);
#pragma unroll
        for (int o = 0; o < 8; ++o) {
          acc0[o] = fmaf(a, wv[o], acc0[o]);
          acc1[o] = fmaf(b2, wv[o], acc1[o]);
        }
      } else if constexpr (COUTB == 6) {
        f32x4 wv = sload4(wp);
        f32x2 wu = sload2(wp + 4);
#pragma unroll
        for (int o = 0; o < 4; ++o) {
          acc0[o] = fmaf(a, wv[o], acc0[o]);
          acc1[o] = fmaf(b2, wv[o], acc1[o]);
        }
#pragma unroll
        for (int o = 0; o < 2; ++o) {
          acc0[4 + o] = fmaf(a, wu[o], acc0[4 + o]);
          acc1[4 + o] = fmaf(b2, wu[o], acc1[4 + o]);
        }
      }
    }
  }

  size_t obase = (size_t)(g * COUTB) * P + (size_t)y * GS + x0;
#pragma unroll
  for (int o = 0; o < COUTB; ++o) {
    float bv = cb[g * COUTB + o];
    float v0 = acc0[o] + bv;
    float v1 = acc1[o] + bv;
    if (RELU) { v0 = fmaxf(v0, 0.f); v1 = fmaxf(v1, 0.f); }
    *(float2*)&out[obase + (size_t)o * P] = make_float2(v0, v1);
  }
}

// ---------------------------------------------------------------------------
extern "C" void kernel_launch(void* const* d_in, const int* in_sizes, int n_in,
                              void* d_out, int out_size, void* d_ws, size_t ws_size,
                              hipStream_t stream) {
  const float* x   = (const float*)d_in[0];
  const int*   esr = (const int*)d_in[1];
  const int*   eds = (const int*)d_in[2];
  const float* W1  = (const float*)d_in[4];
  const float* b1  = (const float*)d_in[5];
  const float* W2  = (const float*)d_in[6];
  const float* b2  = (const float*)d_in[7];
  const float* W3  = (const float*)d_in[8];
  const float* b3  = (const float*)d_in[9];
  const float* cw1 = (const float*)d_in[10];
  const float* cb1 = (const float*)d_in[11];
  const float* cw2 = (const float*)d_in[12];
  const float* cb2 = (const float*)d_in[13];
  const float* cw3 = (const float*)d_in[14];
  const float* cb3 = (const float*)d_in[15];
  const float* cw4 = (const float*)d_in[16];
  const float* cb4 = (const float*)d_in[17];
  float* out = (float*)d_out;

  char* ws = (char*)d_ws;
  const size_t MB = 1 << 20;
  const size_t KB = 1 << 10;
  // Region A [0,65MB): pairs -> xs -> hA (temporally disjoint, stream order)
  unsigned* pairs = (unsigned*)(ws);                 // 8 MB (dead after bsort)
  float*    xs    = (float*)(ws);                    // 4 MB+16B (dead after agg4)
  float*    hA    = (float*)(ws);                    // 64 MB+256B
  // Region B [65MB,130MB): xagg -> hB
  float*    xagg  = (float*)(ws + 65 * MB);          // 4 MB (dead after matmul4)
  float*    hB    = (float*)(ws + 65 * MB);          // 64 MB+256B
  int*      ssrc  = (int*)(ws + 130 * MB);           // 12 MB + margin
  float*    dinv  = (float*)(ws + 142 * MB + 8 * KB);   // 1 MB
  int*      dgr   = (int*)(ws + 143 * MB + 16 * KB);    // 1 MB
  int*      offs  = (int*)(ws + 144 * MB + 24 * KB);    // 1 MB
  int*      gb    = (int*)(ws + 145 * MB + 32 * KB);    // 1 KB
  int*      bbase = (int*)(ws + 145 * MB + 36 * KB);    // 1 KB + 4
  int*      bcur  = (int*)(ws + 145 * MB + 40 * KB);    // 1 KB
  float*    wr1   = (float*)(ws + 145 * MB + 48 * KB);  // 72 KB
  float*    wr2   = wr1 + 64 * 9 * 32;
  float*    wr3   = wr2 + 32 * 9 * 16;
  float*    wr4   = wr3 + 16 * 9 * 8;

  // ---- conv weight repacks ----
  k_wrep<64, 32><<<(64 * 9 * 32 + 255) / 256, 256, 0, stream>>>(cw1, wr1);
  k_wrep<32, 16><<<(32 * 9 * 16 + 255) / 256, 256, 0, stream>>>(cw2, wr2);
  k_wrep<16,  8><<<(16 * 9 *  8 + 255) / 256, 256, 0, stream>>>(cw3, wr3);
  k_wrep< 8,  6><<<( 8 * 9 *  6 + 255) / 256, 256, 0, stream>>>(cw4, wr4);

  // ---- CSR build ----
  hipMemsetAsync(gb, 0, 256 * sizeof(int), stream);
  k_bhist<<<512, 256, 0, stream>>>((const int4*)eds, gb);
  k_bscan<<<1, 256, 0, stream>>>(gb, bbase, bcur);
  k_bin<<<512, 256, 0, stream>>>((const int4*)esr, (const int4*)eds, bcur, pairs);
  k_bsort<<<256, 256, 0, stream>>>(pairs, bbase, ssrc, offs, dgr, dinv);

  // ---- GCN ----
  k_zrows<<<1, 256, 0, stream>>>(hA, hB, xs);
  k_xscale<<<NN / 256, 256, 0, stream>>>((const float4*)x, dinv, (float4*)xs);
  k_agg4<<<1024, 256, 0, stream>>>((const float4*)xs, dinv, offs, dgr,
                                   (const int4*)ssrc, (float4*)xagg);
  k_matmul4<<<2048, 256, 0, stream>>>(xagg, W1, b1, dinv, hA);
  k_aggW<true ><<<2048, 256, 0, stream>>>(hA, dinv, offs, dgr,
                                          (const int4*)ssrc, W2, b2, hB);
  k_aggW<false><<<2048, 256, 0, stream>>>(hB, dinv, offs, dgr,
                                          (const int4*)ssrc, W3, b3, hA);

  // ---- CNN ----
  k_transpose<<<NN / 64, 256, 0, stream>>>(hA, hB);   // [P][64] -> [64][P]
  dim3 cblk(64, 4);
  k_conv<64, 32,  8, true ><<<dim3(4, 128, 4), cblk, 0, stream>>>(hB, wr1, cb1, hA);
  k_conv<32, 16,  8, true ><<<dim3(4, 128, 2), cblk, 0, stream>>>(hA, wr2, cb2, hB);
  k_conv<16,  8,  8, true ><<<dim3(4, 128, 1), cblk, 0, stream>>>(hB, wr3, cb3, hA);
  k_conv< 8,  6,  6, false><<<dim3(4, 128, 1), cblk, 0, stream>>>(hA, wr4, cb4, out);
}

// Round 10
// 578.689 us; speedup vs baseline: 1.3799x; 1.3581x over previous
//
#include <hip/hip_runtime.h>

// Problem constants (fixed by the reference: N = 512*512, E = N*8, grid 512)
#define NN 262144
#define NE 2097152
constexpr int GS = 512;
constexpr int P  = GS * GS;   // == NN
constexpr int BSTRIDE = 12288; // per-bucket ssrc slot stride (4-aligned segs)

typedef __attribute__((ext_vector_type(16))) float f32x16;
typedef __attribute__((ext_vector_type(8)))  float f32x8;
typedef __attribute__((ext_vector_type(4)))  float f32x4;
typedef __attribute__((ext_vector_type(2)))  float f32x2;

// ---------------------------------------------------------------------------
// Whole-channel scalar weight load: N*9 floats in ONE asm block, multiple
// s_loads pipelined in the SMEM unit, single wait INSIDE the block (safe:
// outputs are defined only after the wait; spills/copies see final values).
// "=&s" early-clobber keeps the address pair from being overlapped.
// ---------------------------------------------------------------------------
template <int N> struct WFull;
template <> struct WFull<8> {            // 72 floats
  f32x16 v0, v1, v2, v3; f32x8 v4;
  __device__ __forceinline__ void load(const float* p) {
    asm volatile(
      "s_load_dwordx16 %0, %5, 0x0\n\t"
      "s_load_dwordx16 %1, %5, 0x40\n\t"
      "s_load_dwordx16 %2, %5, 0x80\n\t"
      "s_load_dwordx16 %3, %5, 0xc0\n\t"
      "s_load_dwordx8  %4, %5, 0x100\n\t"
      "s_waitcnt lgkmcnt(0)"
      : "=&s"(v0), "=&s"(v1), "=&s"(v2), "=&s"(v3), "=&s"(v4)
      : "s"(p));
  }
  __device__ __forceinline__ float get(int i) const {   // i compile-time const
    return i < 16 ? v0[i] : i < 32 ? v1[i - 16] : i < 48 ? v2[i - 32]
         : i < 64 ? v3[i - 48] : v4[i - 64];
  }
};
template <> struct WFull<6> {            // 54 floats
  f32x16 v0, v1, v2; f32x4 v3; f32x2 v4;
  __device__ __forceinline__ void load(const float* p) {
    asm volatile(
      "s_load_dwordx16 %0, %5, 0x0\n\t"
      "s_load_dwordx16 %1, %5, 0x40\n\t"
      "s_load_dwordx16 %2, %5, 0x80\n\t"
      "s_load_dwordx4  %3, %5, 0xc0\n\t"
      "s_load_dwordx2  %4, %5, 0xd0\n\t"
      "s_waitcnt lgkmcnt(0)"
      : "=&s"(v0), "=&s"(v1), "=&s"(v2), "=&s"(v3), "=&s"(v4)
      : "s"(p));
  }
  __device__ __forceinline__ float get(int i) const {
    return i < 16 ? v0[i] : i < 32 ? v1[i - 16] : i < 48 ? v2[i - 32]
         : i < 52 ? v3[i - 48] : v4[i - 52];
  }
};

// ---------------------------------------------------------------------------
// CSR build, pass 1: 256-bucket histogram of dst>>10
// ---------------------------------------------------------------------------
__global__ __launch_bounds__(256) void k_bhist(const int4* __restrict__ dst,
                                               int* __restrict__ gb) {
  __shared__ int lc[256];
  int t = threadIdx.x;
  lc[t] = 0;
  __syncthreads();
  int base = blockIdx.x * 1024;            // int4 units; 4096 edges/block
#pragma unroll
  for (int q = 0; q < 4; ++q) {
    int4 d = dst[base + q * 256 + t];
    atomicAdd(&lc[d.x >> 10], 1); atomicAdd(&lc[d.y >> 10], 1);
    atomicAdd(&lc[d.z >> 10], 1); atomicAdd(&lc[d.w >> 10], 1);
  }
  __syncthreads();
  atomicAdd(&gb[t], lc[t]);
}

// exclusive scan of 256 bucket counts -> bbase[257]; copy to bcur
__global__ __launch_bounds__(256) void k_bscan(const int* __restrict__ gb,
                                               int* __restrict__ bbase,
                                               int* __restrict__ bcur) {
  __shared__ int sd[256];
  int t = threadIdx.x;
  sd[t] = gb[t];
  __syncthreads();
  for (int off = 1; off < 256; off <<= 1) {
    int v = (t >= off) ? sd[t - off] : 0;
    __syncthreads();
    sd[t] += v;
    __syncthreads();
  }
  int ex = (t == 0) ? 0 : sd[t - 1];
  bbase[t] = ex;
  bcur[t]  = ex;
  if (t == 255) bbase[256] = sd[255];
}

// pass 2: LDS-binned scatter of packed (dstLocal<<18 | src) into bucket runs.
__global__ __launch_bounds__(256) void k_bin(const int4* __restrict__ src4,
                                             const int4* __restrict__ dst4,
                                             int* __restrict__ bcur,
                                             unsigned* __restrict__ pairs) {
  __shared__ int lcnt[256], lofs[256], lcur[256];
  __shared__ unsigned lp[4096];
  int t = threadIdx.x;
  lcnt[t] = 0;
  __syncthreads();
  int base = blockIdx.x * 1024;
  int4 dreg[4], sreg[4];
#pragma unroll
  for (int q = 0; q < 4; ++q) {
    dreg[q] = dst4[base + q * 256 + t];
    sreg[q] = src4[base + q * 256 + t];
  }
#pragma unroll
  for (int q = 0; q < 4; ++q) {
    atomicAdd(&lcnt[dreg[q].x >> 10], 1); atomicAdd(&lcnt[dreg[q].y >> 10], 1);
    atomicAdd(&lcnt[dreg[q].z >> 10], 1); atomicAdd(&lcnt[dreg[q].w >> 10], 1);
  }
  __syncthreads();
  int c = lcnt[t];
  lofs[t] = c;
  __syncthreads();
  for (int off = 1; off < 256; off <<= 1) {
    int v = (t >= off) ? lofs[t - off] : 0;
    __syncthreads();
    lofs[t] += v;
    __syncthreads();
  }
  int myofs = lofs[t] - c;
  lcur[t] = myofs;
  int gb = atomicAdd(&bcur[t], c);
  __syncthreads();
#pragma unroll
  for (int q = 0; q < 4; ++q) {
    int d[4] = {dreg[q].x, dreg[q].y, dreg[q].z, dreg[q].w};
    int s[4] = {sreg[q].x, sreg[q].y, sreg[q].z, sreg[q].w};
#pragma unroll
    for (int j = 0; j < 4; ++j) {
      int pos = atomicAdd(&lcur[d[j] >> 10], 1);
      lp[pos] = ((unsigned)(d[j] & 1023) << 18) | (unsigned)s[j];
    }
  }
  __syncthreads();
  for (int k = 0; k < c; ++k) pairs[gb + k] = lp[myofs + k];
}

// pass 3: per-bucket counting sort. 4-ALIGNED per-node segments at fixed
// bucket stride; pads = NN (zero row). Direct global scatter (L2-local).
__global__ __launch_bounds__(256) void k_bsort(const unsigned* __restrict__ pairs,
                                               const int* __restrict__ bbase,
                                               int* __restrict__ ssrc,
                                               int* __restrict__ offs,
                                               int* __restrict__ dgr,
                                               float* __restrict__ dinv) {
  __shared__ int cnt[1024], ofs[1024], sblk[256];
  int b = blockIdx.x, t = threadIdx.x;
  int s0 = bbase[b], n = bbase[b + 1] - s0;
  int gbase = b * BSTRIDE;
  // init pad region (pads read as zero-row index)
  for (int i = t; i < BSTRIDE; i += 256) ssrc[gbase + i] = NN;
  for (int i = t; i < 1024; i += 256) cnt[i] = 0;
  __syncthreads();
  for (int i = t; i < n; i += 256) {
    unsigned p = pairs[s0 + i];
    atomicAdd(&cnt[p >> 18], 1);
  }
  __syncthreads();
  int l4 = t * 4;
  int c0 = cnt[l4], c1 = cnt[l4 + 1], c2 = cnt[l4 + 2], c3 = cnt[l4 + 3];
  int a0 = (c0 + 3) & ~3, a1 = (c1 + 3) & ~3, a2 = (c2 + 3) & ~3, a3 = (c3 + 3) & ~3;
  int sum = a0 + a1 + a2 + a3;
  sblk[t] = sum;
  __syncthreads();
  for (int off = 1; off < 256; off <<= 1) {
    int v = (t >= off) ? sblk[t - off] : 0;
    __syncthreads();
    sblk[t] += v;
    __syncthreads();
  }
  int ex = sblk[t] - sum;
  int o0 = gbase + ex, o1 = o0 + a0, o2 = o1 + a1, o3 = o2 + a2;
  ofs[l4] = o0; ofs[l4 + 1] = o1; ofs[l4 + 2] = o2; ofs[l4 + 3] = o3;
  int node = b * 1024 + l4;
  *(int4*)&offs[node] = make_int4(o0, o1, o2, o3);
  *(int4*)&dgr[node]  = make_int4(c0, c1, c2, c3);
  *(float4*)&dinv[node] = make_float4(rsqrtf((float)(c0 + 1)),
                                      rsqrtf((float)(c1 + 1)),
                                      rsqrtf((float)(c2 + 1)),
                                      rsqrtf((float)(c3 + 1)));
  __syncthreads();   // drains init stores before scatter overwrites
  for (int i = t; i < n; i += 256) {
    unsigned p = pairs[s0 + i];
    int pos = atomicAdd(&ofs[p >> 18], 1);
    ssrc[pos] = (int)(p & 0x3FFFFu);
  }
}

// ---------------------------------------------------------------------------
// GCN compute
// ---------------------------------------------------------------------------
// zero rows at index NN (gather target for masked slots)
__global__ void k_zrows(float* hA, float* hB, float* xs) {
  int t = threadIdx.x;
  if (t < 64) hA[(size_t)NN * 64 + t] = 0.f;
  else if (t < 128) hB[(size_t)NN * 64 + (t - 64)] = 0.f;
  else if (t < 132) xs[(size_t)NN * 4 + (t - 128)] = 0.f;
}

// xs = dinv * x  (pre-scaled features)
__global__ __launch_bounds__(256) void k_xscale(const float4* __restrict__ x,
                                                const float* __restrict__ dinv,
                                                float4* __restrict__ xs) {
  int i = blockIdx.x * 256 + threadIdx.x;
  float4 v = x[i];
  float d = dinv[i];
  xs[i] = make_float4(v.x * d, v.y * d, v.z * d, v.w * d);
}

// xagg_i = dinv_i * (sum_{s in N(i)} xs_s + xs_i)
__global__ __launch_bounds__(256) void k_agg4(const float4* __restrict__ xs,
                                              const float* __restrict__ dinv,
                                              const int* __restrict__ offs,
                                              const int* __restrict__ dgr,
                                              const int4* __restrict__ ssrc4,
                                              float4* __restrict__ out) {
  for (int i = blockIdx.x * 256 + threadIdx.x; i < NN; i += gridDim.x * 256) {
    float di = dinv[i];
    int k4 = offs[i] >> 2, deg = dgr[i];
    float4 acc = xs[i];
    int t4n = (deg + 3) >> 2;
    int4 s4 = ssrc4[k4];
    for (int t4 = 0; t4 < t4n; ++t4) {
      int4 nx = ssrc4[k4 + t4 + 1];
      int tb = t4 * 4;
#pragma unroll
      for (int j = 0; j < 4; ++j) {
        int s = (tb + j < deg) ? ((const int*)&s4)[j] : NN;
        float4 v = xs[s];
        acc.x += v.x; acc.y += v.y; acc.z += v.z; acc.w += v.w;
      }
      s4 = nx;
    }
    out[i] = make_float4(acc.x * di, acc.y * di, acc.z * di, acc.w * di);
  }
}

// h1' = relu(xagg @ W1 + b1) * dinv   (pre-scaled for layer-2 gather)
__global__ __launch_bounds__(256) void k_matmul4(const float* __restrict__ h,
                                                 const float* __restrict__ W,
                                                 const float* __restrict__ bias,
                                                 const float* __restrict__ dinv,
                                                 float* __restrict__ out) {
  int lane = threadIdx.x & 63;
  int wv   = threadIdx.x >> 6;
  float w0 = W[lane], w1 = W[64 + lane], w2 = W[128 + lane], w3 = W[192 + lane];
  float bl = bias[lane];
  for (int node = blockIdx.x * 4 + wv; node < NN; node += gridDim.x * 4) {
    float4 hv = *(const float4*)(h + (size_t)node * 4);
    float dn = dinv[node];
    float acc = fmaf(hv.x, w0, fmaf(hv.y, w1, fmaf(hv.z, w2, fmaf(hv.w, w3, bl))));
    out[(size_t)node * 64 + lane] = fmaxf(acc, 0.f) * dn;
  }
}

// Fused GCN layer on pre-scaled rows h' : out = relu( (di * sum h'_s) W + b )
// [* dinv if SCALE_OUT]. 4 nodes/wave; each 16-lane group iterates only its
// OWN ceil(deg/4) int4 slots. Masked tail slots -> zero row NN. Matvec:
// rotation reads of duplicated 512B LDS row vs diagonal-rotated W per-lane.
template <bool SCALE_OUT>
__global__ __launch_bounds__(256) void k_aggW(const float* __restrict__ h,
                                              const float* __restrict__ dinv,
                                              const int* __restrict__ offs,
                                              const int* __restrict__ dgr,
                                              const int4* __restrict__ ssrc4,
                                              const float* __restrict__ W,
                                              const float* __restrict__ bias,
                                              float* __restrict__ out) {
  __shared__ float g[16][128];               // duplicated rows: [d] and [d+64]
  const float4* h4 = (const float4*)h;
  int lane = threadIdx.x & 63;
  int wv   = threadIdx.x >> 6;
  int sub  = lane >> 4;        // node slot (0..3)
  int fl   = lane & 15;        // float4 index within row
  int rot  = lane & 15;        // rotation base for matvec
  // diagonal-rotated weights: wrot[q*4+j] = W[4*((rot+q)&15)+j][lane]
  float wrot[64];
#pragma unroll
  for (int q = 0; q < 16; ++q) {
    int kb = 4 * ((rot + q) & 15);
#pragma unroll
    for (int j = 0; j < 4; ++j) wrot[q * 4 + j] = W[(size_t)(kb + j) * 64 + lane];
  }
  float bl = bias[lane];

  for (int i0 = (blockIdx.x * 4 + wv) * 4; i0 < NN; i0 += gridDim.x * 16) {
    int i = i0 + sub;
    float di = dinv[i];
    int k4 = offs[i] >> 2;
    int deg = dgr[i];
    int t4n = (deg + 3) >> 2;

    float4 acc = h4[(size_t)i * 16 + fl];    // self term (h' already scaled)
    int4 s4 = ssrc4[k4];
#pragma unroll 2
    for (int t4 = 0; t4 < t4n; ++t4) {
      int4 nx = ssrc4[k4 + t4 + 1];
      int tb = t4 * 4;
#pragma unroll
      for (int j = 0; j < 4; ++j) {
        int s = (tb + j < deg) ? ((const int*)&s4)[j] : NN;
        float4 v = h4[(size_t)s * 16 + fl];
        acc.x += v.x; acc.y += v.y; acc.z += v.z; acc.w += v.w;
      }
      s4 = nx;
    }

    // park di*acc twice (no-wrap rotation window)
    float4 sacc = make_float4(acc.x * di, acc.y * di, acc.z * di, acc.w * di);
    int row = wv * 4 + sub;
    *(float4*)&g[row][fl * 4]      = sacc;
    *(float4*)&g[row][fl * 4 + 64] = sacc;
    asm volatile("s_waitcnt lgkmcnt(0)" ::: "memory");

#pragma unroll
    for (int n = 0; n < 4; ++n) {
      const float4* gp = (const float4*)&g[wv * 4 + n][rot * 4];
      float o = bl;
#pragma unroll
      for (int q = 0; q < 16; ++q) {
        float4 gv = gp[q];
        o = fmaf(gv.x, wrot[q * 4 + 0], o);
        o = fmaf(gv.y, wrot[q * 4 + 1], o);
        o = fmaf(gv.z, wrot[q * 4 + 2], o);
        o = fmaf(gv.w, wrot[q * 4 + 3], o);
      }
      float val = fmaxf(o, 0.f);
      if (SCALE_OUT) val *= dinv[i0 + n];
      out[(size_t)(i0 + n) * 64 + lane] = val;
    }
  }
}

// channels-last [P][64] -> planar [64][P]
__global__ __launch_bounds__(256) void k_transpose(const float* __restrict__ in,
                                                   float* __restrict__ out) {
  __shared__ float t[64][65];
  int tx = threadIdx.x & 63;
  int ty = threadIdx.x >> 6;
  int base = blockIdx.x * 64;
#pragma unroll
  for (int i = 0; i < 16; ++i) {
    int p = ty + i * 4;
    t[p][tx] = in[(size_t)(base + p) * 64 + tx];
  }
  __syncthreads();
#pragma unroll
  for (int i = 0; i < 16; ++i) {
    int c = ty + i * 4;
    out[(size_t)c * P + base + tx] = t[tx][c];
  }
}

// Repack conv weights OIHW -> group-major [g][c][tap][o_in_group]
// so each (group, channel) block is 9*COUTB contiguous floats.
template <int CIN, int COUT, int COUTB>
__global__ __launch_bounds__(256) void k_wrep(const float* __restrict__ w,
                                              float* __restrict__ wr) {
  int i = blockIdx.x * 256 + threadIdx.x;
  if (i >= CIN * 9 * COUT) return;
  int ol = i % COUTB;
  int t  = (i / COUTB) % 9;
  int c  = (i / (COUTB * 9)) % CIN;
  int g  = i / (COUTB * 9 * CIN);
  wr[i] = w[(((g * COUTB + ol) * CIN) + c) * 9 + t];
}

// ---------------------------------------------------------------------------
// Planar 3x3 SAME conv, 2 px/thread, COUTB outs per block (z = group).
// Per input channel: ONE pipelined s_load block (5 loads + 1 wait) for all
// 9*COUTB weights, then 9 taps x 2*COUTB FMAs.
// ---------------------------------------------------------------------------
template <int CIN, int COUTB, bool RELU>
__global__ __launch_bounds__(256) void k_conv(const float* __restrict__ in,
                                              const float* __restrict__ wrep,
                                              const float* __restrict__ cb,
                                              float* __restrict__ out) {
  int tx = threadIdx.x;          // 0..63
  int ty = threadIdx.y;          // 0..3
  int g  = blockIdx.z;
  int x0 = (blockIdx.x * 64 + tx) * 2;
  int y  = blockIdx.y * 4 + ty;

  float acc0[COUTB], acc1[COUTB];
#pragma unroll
  for (int o = 0; o < COUTB; ++o) { acc0[o] = 0.f; acc1[o] = 0.f; }

  bool xlo = x0 > 0;
  bool xhi = x0 < GS - 2;
  int rok[3], yoff[3];
#pragma unroll
  for (int r = 0; r < 3; ++r) {
    int yy = y + r - 1;
    rok[r] = (yy >= 0) && (yy < GS);
    int yc = yy < 0 ? 0 : (yy > GS - 1 ? GS - 1 : yy);
    yoff[r] = yc * GS;
  }
  const float* wg = wrep + (size_t)g * CIN * 9 * COUTB;

  WFull<COUTB> w;
#pragma unroll 1
  for (int c = 0; c < CIN; ++c) {
    float iv[3][4];
#pragma unroll
    for (int r = 0; r < 3; ++r) {
      const float* ip = in + (size_t)c * P + yoff[r] + x0;
      if (rok[r]) {
        float2 m = *(const float2*)ip;
        iv[r][1] = m.x; iv[r][2] = m.y;
        iv[r][0] = xlo ? ip[-1] : 0.f;
        iv[r][3] = xhi ? ip[2]  : 0.f;
      } else {
        iv[r][0] = iv[r][1] = iv[r][2] = iv[r][3] = 0.f;
      }
    }
    w.load(wg + (size_t)c * 9 * COUTB);
#pragma unroll
    for (int t9 = 0; t9 < 9; ++t9) {
      int ky = t9 / 3, kx = t9 % 3;
      float a = iv[ky][kx], b2 = iv[ky][kx + 1];
#pragma unroll
      for (int o = 0; o < COUTB; ++o) {
        float wv = w.get(t9 * COUTB + o);
        acc0[o] = fmaf(a, wv, acc0[o]);
        acc1[o] = fmaf(b2, wv, acc1[o]);
      }
    }
  }

  size_t obase = (size_t)(g * COUTB) * P + (size_t)y * GS + x0;
#pragma unroll
  for (int o = 0; o < COUTB; ++o) {
    float bv = cb[g * COUTB + o];
    float v0 = acc0[o] + bv;
    float v1 = acc1[o] + bv;
    if (RELU) { v0 = fmaxf(v0, 0.f); v1 = fmaxf(v1, 0.f); }
    *(float2*)&out[obase + (size_t)o * P] = make_float2(v0, v1);
  }
}

// ---------------------------------------------------------------------------
extern "C" void kernel_launch(void* const* d_in, const int* in_sizes, int n_in,
                              void* d_out, int out_size, void* d_ws, size_t ws_size,
                              hipStream_t stream) {
  const float* x   = (const float*)d_in[0];
  const int*   esr = (const int*)d_in[1];
  const int*   eds = (const int*)d_in[2];
  const float* W1  = (const float*)d_in[4];
  const float* b1  = (const float*)d_in[5];
  const float* W2  = (const float*)d_in[6];
  const float* b2  = (const float*)d_in[7];
  const float* W3  = (const float*)d_in[8];
  const float* b3  = (const float*)d_in[9];
  const float* cw1 = (const float*)d_in[10];
  const float* cb1 = (const float*)d_in[11];
  const float* cw2 = (const float*)d_in[12];
  const float* cb2 = (const float*)d_in[13];
  const float* cw3 = (const float*)d_in[14];
  const float* cb3 = (const float*)d_in[15];
  const float* cw4 = (const float*)d_in[16];
  const float* cb4 = (const float*)d_in[17];
  float* out = (float*)d_out;

  char* ws = (char*)d_ws;
  const size_t MB = 1 << 20;
  const size_t KB = 1 << 10;
  // Region A [0,65MB): pairs -> xs -> hA (temporally disjoint, stream order)
  unsigned* pairs = (unsigned*)(ws);                 // 8 MB (dead after bsort)
  float*    xs    = (float*)(ws);                    // 4 MB+16B (dead after agg4)
  float*    hA    = (float*)(ws);                    // 64 MB+256B
  // Region B [65MB,130MB): xagg -> hB
  float*    xagg  = (float*)(ws + 65 * MB);          // 4 MB (dead after matmul4)
  float*    hB    = (float*)(ws + 65 * MB);          // 64 MB+256B
  int*      ssrc  = (int*)(ws + 130 * MB);           // 12 MB + margin
  float*    dinv  = (float*)(ws + 142 * MB + 8 * KB);   // 1 MB
  int*      dgr   = (int*)(ws + 143 * MB + 16 * KB);    // 1 MB
  int*      offs  = (int*)(ws + 144 * MB + 24 * KB);    // 1 MB
  int*      gb    = (int*)(ws + 145 * MB + 32 * KB);    // 1 KB
  int*      bbase = (int*)(ws + 145 * MB + 36 * KB);    // 1 KB + 4
  int*      bcur  = (int*)(ws + 145 * MB + 40 * KB);    // 1 KB
  float*    wr1   = (float*)(ws + 145 * MB + 48 * KB);  // 72 KB
  float*    wr2   = wr1 + 64 * 9 * 32;
  float*    wr3   = wr2 + 32 * 9 * 16;
  float*    wr4   = wr3 + 16 * 9 * 8;

  // ---- conv weight repacks (group-major) ----
  k_wrep<64, 32, 8><<<(64 * 9 * 32 + 255) / 256, 256, 0, stream>>>(cw1, wr1);
  k_wrep<32, 16, 8><<<(32 * 9 * 16 + 255) / 256, 256, 0, stream>>>(cw2, wr2);
  k_wrep<16,  8, 8><<<(16 * 9 *  8 + 255) / 256, 256, 0, stream>>>(cw3, wr3);
  k_wrep< 8,  6, 6><<<( 8 * 9 *  6 + 255) / 256, 256, 0, stream>>>(cw4, wr4);

  // ---- CSR build ----
  hipMemsetAsync(gb, 0, 256 * sizeof(int), stream);
  k_bhist<<<512, 256, 0, stream>>>((const int4*)eds, gb);
  k_bscan<<<1, 256, 0, stream>>>(gb, bbase, bcur);
  k_bin<<<512, 256, 0, stream>>>((const int4*)esr, (const int4*)eds, bcur, pairs);
  k_bsort<<<256, 256, 0, stream>>>(pairs, bbase, ssrc, offs, dgr, dinv);

  // ---- GCN ----
  k_zrows<<<1, 256, 0, stream>>>(hA, hB, xs);
  k_xscale<<<NN / 256, 256, 0, stream>>>((const float4*)x, dinv, (float4*)xs);
  k_agg4<<<1024, 256, 0, stream>>>((const float4*)xs, dinv, offs, dgr,
                                   (const int4*)ssrc, (float4*)xagg);
  k_matmul4<<<2048, 256, 0, stream>>>(xagg, W1, b1, dinv, hA);
  k_aggW<true ><<<2048, 256, 0, stream>>>(hA, dinv, offs, dgr,
                                          (const int4*)ssrc, W2, b2, hB);
  k_aggW<false><<<2048, 256, 0, stream>>>(hB, dinv, offs, dgr,
                                          (const int4*)ssrc, W3, b3, hA);

  // ---- CNN ----
  k_transpose<<<NN / 64, 256, 0, stream>>>(hA, hB);   // [P][64] -> [64][P]
  dim3 cblk(64, 4);
  k_conv<64, 8, true ><<<dim3(4, 128, 4), cblk, 0, stream>>>(hB, wr1, cb1, hA);
  k_conv<32, 8, true ><<<dim3(4, 128, 2), cblk, 0, stream>>>(hA, wr2, cb2, hB);
  k_conv<16, 8, true ><<<dim3(4, 128, 1), cblk, 0, stream>>>(hB, wr3, cb3, hA);
  k_conv< 8, 6, false><<<dim3(4, 128, 1), cblk, 0, stream>>>(hA, wr4, cb4, out);
}